// Round 10
// baseline (165.536 us; speedup 1.0000x reference)
//
#include <hip/hip_runtime.h>

#define LAT_SHAPE 1801
#define LON_SHAPE 3600
#define NPTS 2000000

typedef float f32x4 __attribute__((ext_vector_type(4)));

// g6/g7 staging and the output-packing buffer are live in disjoint phases;
// union them so total LDS stays 16.5KB -> 8 blocks/CU (full 32 waves/CU).
union SharedU {
    struct { float g6s[1653]; float g7s[435]; } g;   // 8.3KB
    f32x4 obuf[1024];                                // 16KB (512 points x 2)
};

__global__ __launch_bounds__(256, 8) void le_kernel(
    const float2* __restrict__ x,
    const float* __restrict__ g0, const float* __restrict__ g1,
    const float* __restrict__ g2, const float* __restrict__ g3,
    const float* __restrict__ g4, const float* __restrict__ g5,
    const float* __restrict__ g6, const float* __restrict__ g7,
    float* __restrict__ out, int n)
{
#pragma clang fp contract(off)
    __shared__ SharedU sh;

    const int base = blockIdx.x * 512;          // 512 points per block
    int iA = base + threadIdx.x;
    int iB = base + 256 + threadIdx.x;
    int cA = min(iA, n - 1);                    // tail: duplicate last point
    int cB = min(iB, n - 1);
    float2 pA = x[cA];                          // issued before staging barrier
    float2 pB = x[cB];

    for (int k = threadIdx.x; k < 1653; k += 256) sh.g.g6s[k] = g6[k];
    for (int k = threadIdx.x; k < 435; k += 256) sh.g.g7s[k] = g7[k];
    __syncthreads();   // drains only x/staging loads; gathers not yet issued

    // FROZEN MATH (bit-exact vs np golden, round 5): f32, *10.0f, ties-even.
    int yiA = (int)rintf((90.0f - pA.x) * 10.0f);
    int xiA = (int)rintf(pA.y * 10.0f);
    int yiB = (int)rintf((90.0f - pB.x) * 10.0f);
    int xiB = (int)rintf(pB.y * 10.0f);
    yiA = min(max(yiA, 0), LAT_SHAPE - 1); xiA = min(max(xiA, 0), LON_SHAPE - 1);
    yiB = min(max(yiB, 0), LAT_SHAPE - 1); xiB = min(max(xiB, 0), LON_SHAPE - 1);

    // ---- Phase 1: issue ALL 42 global gathers for BOTH points -------------
    float r0A = g0[yiA * LON_SHAPE + xiA];      // level 0 first (miss-prone)
    float r0B = g0[yiB * LON_SHAPE + xiB];

    constexpr int H[5] = {901, 451, 226, 113, 57};    // levels 1..5
    constexpr int W[5] = {1800, 900, 450, 225, 113};
    constexpr float SCY[5] = {
        (float)(901.0 / 1801.0), (float)(451.0 / 1801.0), (float)(226.0 / 1801.0),
        (float)(113.0 / 1801.0), (float)(57.0 / 1801.0)};
    constexpr float SCX[5] = {
        (float)(1800.0 / 3600.0), (float)(900.0 / 3600.0), (float)(450.0 / 3600.0),
        (float)(225.0 / 3600.0), (float)(113.0 / 3600.0)};

    const float* gg[5] = {g1, g2, g3, g4, g5};
    const float yifA = (float)yiA, xifA = (float)xiA;
    const float yifB = (float)yiB, xifB = (float)xiB;

    float vvA[5][4], vvB[5][4];
    float wyA[5], wxA[5], wyB[5], wxB[5];

#pragma unroll
    for (int i = 0; i < 5; ++i) {
        const float* __restrict__ g = gg[i];
        {
            float sy = fmaxf((yifA + 0.5f) * SCY[i] - 0.5f, 0.0f);
            float sx = fmaxf((xifA + 0.5f) * SCX[i] - 0.5f, 0.0f);
            int y0 = (int)sy, x0 = (int)sx;
            wyA[i] = sy - (float)y0; wxA[i] = sx - (float)x0;
            int y1 = min(y0 + 1, H[i] - 1), x1 = min(x0 + 1, W[i] - 1);
            vvA[i][0] = g[y0 * W[i] + x0];
            vvA[i][1] = g[y0 * W[i] + x1];
            vvA[i][2] = g[y1 * W[i] + x0];
            vvA[i][3] = g[y1 * W[i] + x1];
        }
        {
            float sy = fmaxf((yifB + 0.5f) * SCY[i] - 0.5f, 0.0f);
            float sx = fmaxf((xifB + 0.5f) * SCX[i] - 0.5f, 0.0f);
            int y0 = (int)sy, x0 = (int)sx;
            wyB[i] = sy - (float)y0; wxB[i] = sx - (float)x0;
            int y1 = min(y0 + 1, H[i] - 1), x1 = min(x0 + 1, W[i] - 1);
            vvB[i][0] = g[y0 * W[i] + x0];
            vvB[i][1] = g[y0 * W[i] + x1];
            vvB[i][2] = g[y1 * W[i] + x0];
            vvB[i][3] = g[y1 * W[i] + x1];
        }
    }

    // HARD scheduling fence: nothing crosses. All 42 loads are now issued and
    // their results must stay live -> compiler cannot re-serialize them.
    __builtin_amdgcn_sched_barrier(0);

    // ---- Phase 2: LDS levels 6..7 (lgkm-only waits; vmem still in flight) --
    constexpr int HL[2] = {29, 15};
    constexpr int WL[2] = {57, 29};
    constexpr float LSY[2] = {(float)(29.0 / 1801.0), (float)(15.0 / 1801.0)};
    constexpr float LSX[2] = {(float)(57.0 / 3600.0), (float)(29.0 / 3600.0)};
    float l67A[2], l67B[2];
#pragma unroll
    for (int i = 0; i < 2; ++i) {
        const float* g = (i == 0) ? sh.g.g6s : sh.g.g7s;
        {
            float sy = fmaxf((yifA + 0.5f) * LSY[i] - 0.5f, 0.0f);
            float sx = fmaxf((xifA + 0.5f) * LSX[i] - 0.5f, 0.0f);
            int y0 = (int)sy, x0 = (int)sx;
            float wy = sy - (float)y0, wx = sx - (float)x0;
            int y1 = min(y0 + 1, HL[i] - 1), x1 = min(x0 + 1, WL[i] - 1);
            float v00 = g[y0 * WL[i] + x0], v01 = g[y0 * WL[i] + x1];
            float v10 = g[y1 * WL[i] + x0], v11 = g[y1 * WL[i] + x1];
            float omwy = 1.0f - wy, omwx = 1.0f - wx;
            l67A[i] = v00 * omwy * omwx + v01 * omwy * wx
                    + v10 * wy * omwx + v11 * wy * wx;
        }
        {
            float sy = fmaxf((yifB + 0.5f) * LSY[i] - 0.5f, 0.0f);
            float sx = fmaxf((xifB + 0.5f) * LSX[i] - 0.5f, 0.0f);
            int y0 = (int)sy, x0 = (int)sx;
            float wy = sy - (float)y0, wx = sx - (float)x0;
            int y1 = min(y0 + 1, HL[i] - 1), x1 = min(x0 + 1, WL[i] - 1);
            float v00 = g[y0 * WL[i] + x0], v01 = g[y0 * WL[i] + x1];
            float v10 = g[y1 * WL[i] + x0], v11 = g[y1 * WL[i] + x1];
            float omwy = 1.0f - wy, omwx = 1.0f - wx;
            l67B[i] = v00 * omwy * omwx + v01 * omwy * wx
                    + v10 * wy * omwx + v11 * wy * wx;
        }
    }

    // ---- Phase 3: blends (consume gathers in issue order) ------------------
    float resA[8], resB[8];
    resA[0] = r0A; resB[0] = r0B;      // level 0: blend collapses to v00
    resA[6] = l67A[0]; resA[7] = l67A[1];
    resB[6] = l67B[0]; resB[7] = l67B[1];
#pragma unroll
    for (int i = 0; i < 5; ++i) {
        {
            float wy = wyA[i], wx = wxA[i];
            float omwy = 1.0f - wy, omwx = 1.0f - wx;
            resA[1 + i] = vvA[i][0] * omwy * omwx + vvA[i][1] * omwy * wx
                        + vvA[i][2] * wy * omwx + vvA[i][3] * wy * wx;
        }
        {
            float wy = wyB[i], wx = wxB[i];
            float omwy = 1.0f - wy, omwx = 1.0f - wx;
            resB[1 + i] = vvB[i][0] * omwy * omwx + vvB[i][1] * omwy * wx
                        + vvB[i][2] * wy * omwx + vvB[i][3] * wy * wx;
        }
    }

    // Union repurpose barrier: all g6s/g7s reads are done block-wide; vmcnt is
    // already drained by consumption, so this barrier costs only the sync.
    __syncthreads();

    // ---- Pack through LDS: stores cover contiguous 1KB ranges --------------
    int t = threadIdx.x;
    sh.obuf[2 * t]           = (f32x4){resA[0], resA[1], resA[2], resA[3]};
    sh.obuf[2 * t + 1]       = (f32x4){resA[4], resA[5], resA[6], resA[7]};
    sh.obuf[512 + 2 * t]     = (f32x4){resB[0], resB[1], resB[2], resB[3]};
    sh.obuf[512 + 2 * t + 1] = (f32x4){resB[4], resB[5], resB[6], resB[7]};
    __syncthreads();

    const size_t total_f4 = (size_t)n * 2;
    const size_t fb = (size_t)blockIdx.x * 1024;
    f32x4* o4 = (f32x4*)out;
#pragma unroll
    for (int k = 0; k < 4; ++k) {
        size_t off = fb + k * 256 + t;
        if (off < total_f4)
            __builtin_nontemporal_store(sh.obuf[k * 256 + t], &o4[off]);
    }
}

extern "C" void kernel_launch(void* const* d_in, const int* in_sizes, int n_in,
                              void* d_out, int out_size, void* d_ws, size_t ws_size,
                              hipStream_t stream) {
    // Assign roles by unique element count (robust to input permutation).
    const int GSZ[8] = {6483600, 1621800, 405900, 101700, 25425, 6441, 1653, 435};
    const float* xp = nullptr;
    const float* g[8] = {nullptr};
    int n = 0;
    for (int i = 0; i < n_in; ++i) {
        int s = in_sizes[i];
        if (s == 2 * NPTS) { xp = (const float*)d_in[i]; n = NPTS; continue; }
        for (int l = 0; l < 8; ++l)
            if (s == GSZ[l]) { g[l] = (const float*)d_in[i]; break; }
    }
    if (!xp) { xp = (const float*)d_in[0]; n = in_sizes[0] / 2; }
    for (int l = 0; l < 8; ++l)
        if (!g[l]) g[l] = (const float*)d_in[1 + l];

    int blocks = (n + 511) / 512;   // 512 points per block (2 per thread)
    le_kernel<<<blocks, 256, 0, stream>>>((const float2*)xp, g[0], g[1], g[2],
                                          g[3], g[4], g[5], g[6], g[7],
                                          (float*)d_out, n);
}

// Round 12
// 156.225 us; speedup vs baseline: 1.0596x; 1.0596x over previous
//
#include <hip/hip_runtime.h>

#define LAT_SHAPE 1801
#define LON_SHAPE 3600
#define NPTS 2000000

typedef float f32x4 __attribute__((ext_vector_type(4)));
typedef float f32x2 __attribute__((ext_vector_type(2)));

// 8B load with only 4B alignment guarantee (x0 may be odd). Lowers to
// global_load_dwordx2 on CDNA (unaligned-dword access supported); worst
// case the compiler splits it into 2 dwords = previous behavior.
__device__ __forceinline__ f32x2 load_pair(const float* p) {
    f32x2 v;
    __builtin_memcpy(&v, p, 8);
    return v;
}

__global__ __launch_bounds__(256) void le_kernel(
    const float2* __restrict__ x,
    const float* __restrict__ g0, const float* __restrict__ g1,
    const float* __restrict__ g2, const float* __restrict__ g3,
    const float* __restrict__ g4, const float* __restrict__ g5,
    const float* __restrict__ g6, const float* __restrict__ g7,
    float* __restrict__ out, int n)
{
#pragma clang fp contract(off)
    __shared__ float g6s[1653];   // 29 x 57
    __shared__ float g7s[435];    // 15 x 29
    __shared__ f32x4 obuf[512];

    int idx = blockIdx.x * blockDim.x + threadIdx.x;
    int cidx = min(idx, n - 1);   // tail threads duplicate last point
    float2 p = x[cidx];           // issue before staging barrier

    for (int k = threadIdx.x; k < 1653; k += 256) g6s[k] = g6[k];
    for (int k = threadIdx.x; k < 435; k += 256) g7s[k] = g7[k];
    __syncthreads();              // drains staging loads only

    // FROZEN MATH (bit-exact vs np golden, round 5): f32, *10.0f, ties-even.
    int yi = (int)rintf((90.0f - p.x) * 10.0f);
    int xi = (int)rintf(p.y * 10.0f);
    yi = min(max(yi, 0), LAT_SHAPE - 1);
    xi = min(max(xi, 0), LON_SHAPE - 1);

    float res[8];
    // Level 0: scale exactly 1.0 -> blend collapses to v00. Single gather.
    res[0] = g0[yi * LON_SHAPE + xi];

    constexpr int H[5] = {901, 451, 226, 113, 57};    // levels 1..5
    constexpr int W[5] = {1800, 900, 450, 225, 113};
    constexpr float SCY[5] = {
        (float)(901.0 / 1801.0), (float)(451.0 / 1801.0), (float)(226.0 / 1801.0),
        (float)(113.0 / 1801.0), (float)(57.0 / 1801.0)};
    constexpr float SCX[5] = {
        (float)(1800.0 / 3600.0), (float)(900.0 / 3600.0), (float)(450.0 / 3600.0),
        (float)(225.0 / 3600.0), (float)(113.0 / 3600.0)};

    const float* gg[5] = {g1, g2, g3, g4, g5};
    const float yif = (float)yi;
    const float xif = (float)xi;

    f32x2 pa[5], pb[5];           // horizontal pairs: row y0, row y1
    float wyA[5], wxA[5];
    bool hiA[5];

    // ---- Gather phase: 10 pair-loads (2/level), adjacent-pixel fusion -----
#pragma unroll
    for (int i = 0; i < 5; ++i) {
        float sy = fmaxf((yif + 0.5f) * SCY[i] - 0.5f, 0.0f);
        float sx = fmaxf((xif + 0.5f) * SCX[i] - 0.5f, 0.0f);
        int y0 = (int)sy;            // floor: sy >= 0
        int x0 = (int)sx;
        wyA[i] = sy - (float)y0;
        wxA[i] = sx - (float)x0;
        int y1 = min(y0 + 1, H[i] - 1);
        int xb = min(x0, W[i] - 2);  // pair covers {v00,v01} incl. x-clamp
        hiA[i] = x0 > xb;            // x0 == W-1 (clamped): v00 = pair.y
        const float* __restrict__ g = gg[i];
        pa[i] = load_pair(g + y0 * W[i] + xb);
        pb[i] = load_pair(g + y1 * W[i] + xb);
    }

    // ---- LDS levels 6..7 (lgkm waits only; global pairs still in flight) --
    {
        constexpr int HL[2] = {29, 15};
        constexpr int WL[2] = {57, 29};
        constexpr float LSY[2] = {(float)(29.0 / 1801.0), (float)(15.0 / 1801.0)};
        constexpr float LSX[2] = {(float)(57.0 / 3600.0), (float)(29.0 / 3600.0)};
        float r[2];
#pragma unroll
        for (int i = 0; i < 2; ++i) {
            const float* g = (i == 0) ? g6s : g7s;
            float sy = fmaxf((yif + 0.5f) * LSY[i] - 0.5f, 0.0f);
            float sx = fmaxf((xif + 0.5f) * LSX[i] - 0.5f, 0.0f);
            int y0 = (int)sy, x0 = (int)sx;
            float wy = sy - (float)y0, wx = sx - (float)x0;
            int y1 = min(y0 + 1, HL[i] - 1), x1 = min(x0 + 1, WL[i] - 1);
            float v00 = g[y0 * WL[i] + x0], v01 = g[y0 * WL[i] + x1];
            float v10 = g[y1 * WL[i] + x0], v11 = g[y1 * WL[i] + x1];
            float omwy = 1.0f - wy, omwx = 1.0f - wx;
            r[i] = v00 * omwy * omwx + v01 * omwy * wx
                 + v10 * wy * omwx + v11 * wy * wx;
        }
        res[6] = r[0];
        res[7] = r[1];
    }

    // ---- Blend levels 1..5 (exact frozen form; selects feed exact values) --
#pragma unroll
    for (int i = 0; i < 5; ++i) {
        float v00 = hiA[i] ? pa[i].y : pa[i].x;
        float v01 = pa[i].y;
        float v10 = hiA[i] ? pb[i].y : pb[i].x;
        float v11 = pb[i].y;
        float wy = wyA[i], wx = wxA[i];
        float omwy = 1.0f - wy, omwx = 1.0f - wx;
        res[1 + i] = v00 * omwy * omwx + v01 * omwy * wx
                   + v10 * wy * omwx + v11 * wy * wx;
    }

    // ---- Pack through LDS: each store covers a contiguous 1KB range -------
    f32x4 lo = {res[0], res[1], res[2], res[3]};
    f32x4 hi = {res[4], res[5], res[6], res[7]};
    obuf[2 * threadIdx.x]     = lo;
    obuf[2 * threadIdx.x + 1] = hi;
    __syncthreads();

    const size_t total_f4 = (size_t)n * 2;
    const size_t base = (size_t)blockIdx.x * 512;
    f32x4* o4 = (f32x4*)out;
    int t = threadIdx.x;
    if (base + t < total_f4)
        __builtin_nontemporal_store(obuf[t], &o4[base + t]);
    if (base + 256 + t < total_f4)
        __builtin_nontemporal_store(obuf[256 + t], &o4[base + 256 + t]);
}

extern "C" void kernel_launch(void* const* d_in, const int* in_sizes, int n_in,
                              void* d_out, int out_size, void* d_ws, size_t ws_size,
                              hipStream_t stream) {
    // Assign roles by unique element count (robust to input permutation).
    const int GSZ[8] = {6483600, 1621800, 405900, 101700, 25425, 6441, 1653, 435};
    const float* xp = nullptr;
    const float* g[8] = {nullptr};
    int n = 0;
    for (int i = 0; i < n_in; ++i) {
        int s = in_sizes[i];
        if (s == 2 * NPTS) { xp = (const float*)d_in[i]; n = NPTS; continue; }
        for (int l = 0; l < 8; ++l)
            if (s == GSZ[l]) { g[l] = (const float*)d_in[i]; break; }
    }
    if (!xp) { xp = (const float*)d_in[0]; n = in_sizes[0] / 2; }
    for (int l = 0; l < 8; ++l)
        if (!g[l]) g[l] = (const float*)d_in[1 + l];

    int blocks = (n + 255) / 256;
    le_kernel<<<blocks, 256, 0, stream>>>((const float2*)xp, g[0], g[1], g[2],
                                          g[3], g[4], g[5], g[6], g[7],
                                          (float*)d_out, n);
}

// Round 13
// 150.550 us; speedup vs baseline: 1.0995x; 1.0377x over previous
//
#include <hip/hip_runtime.h>

#define LAT_SHAPE 1801
#define LON_SHAPE 3600
#define NPTS 2000000
#define NBAND 16
#define BROWS 113   // rows per band: 16*113 = 1808 >= 1801

typedef float f32x4 __attribute__((ext_vector_type(4)));
typedef float f32x2 __attribute__((ext_vector_type(2)));

// FROZEN MATH (bit-exact vs np golden, round 5): f32, *10.0f, ties-even.
__device__ __forceinline__ void coord2idx(float lat, float lon, int& yi, int& xi) {
    yi = (int)rintf((90.0f - lat) * 10.0f);
    xi = (int)rintf(lon * 10.0f);
    yi = min(max(yi, 0), LAT_SHAPE - 1);
    xi = min(max(xi, 0), LON_SHAPE - 1);
}

__device__ __forceinline__ f32x2 load_pair(const float* p) {
    f32x2 v; __builtin_memcpy(&v, p, 8); return v;
}

// ---- Pass A: per-block 16-bin histogram (LDS only; no global atomics) ----
__global__ __launch_bounds__(256) void hist_k(const float2* __restrict__ x, int n,
                                              int nblkS, unsigned* __restrict__ cnt) {
    __shared__ unsigned h[NBAND];
    if (threadIdx.x < NBAND) h[threadIdx.x] = 0;
    __syncthreads();
    int i = blockIdx.x * 256 + threadIdx.x;
    if (i < n) {
        float2 p = x[i];
        int yi, xi; coord2idx(p.x, p.y, yi, xi);
        atomicAdd(&h[yi / BROWS], 1u);
    }
    __syncthreads();
    if (threadIdx.x < NBAND)
        cnt[(size_t)threadIdx.x * nblkS + blockIdx.x] = h[threadIdx.x];
}

// ---- Pass B1: per-band exclusive scan over blocks, in place ----
__global__ __launch_bounds__(256) void scanband_k(unsigned* __restrict__ cnt, int nblkS,
                                                  unsigned* __restrict__ bandTotal) {
    unsigned* a = cnt + (size_t)blockIdx.x * nblkS;
    int chunk = (nblkS + 255) / 256;
    int t = threadIdx.x;
    int lo = t * chunk, hi = min(nblkS, lo + chunk);
    unsigned s = 0;
    for (int k = lo; k < hi; ++k) s += a[k];
    __shared__ unsigned ls[256];
    ls[t] = s;
    __syncthreads();
    for (int off = 1; off < 256; off <<= 1) {   // inclusive Hillis-Steele
        unsigned v = (t >= off) ? ls[t - off] : 0u;
        __syncthreads();
        ls[t] += v;
        __syncthreads();
    }
    unsigned run = (t == 0) ? 0u : ls[t - 1];
    for (int k = lo; k < hi; ++k) { unsigned v = a[k]; a[k] = run; run += v; }
    if (t == 255) bandTotal[blockIdx.x] = ls[255];
}

// ---- Pass B2: band bases (16 values, serial) ----
__global__ void bandbase_k(const unsigned* __restrict__ bandTotal,
                           unsigned* __restrict__ bandBase) {
    if (threadIdx.x == 0) {
        unsigned acc = 0;
        for (int b = 0; b < NBAND; ++b) { bandBase[b] = acc; acc += bandTotal[b]; }
        bandBase[NBAND] = acc;
    }
}

// ---- Pass C: scatter records; ranks via LDS atomics (output-invariant) ----
__global__ __launch_bounds__(256) void scatter_k(const float2* __restrict__ x, int n,
                                                 int nblkS,
                                                 const unsigned* __restrict__ cnt,
                                                 const unsigned* __restrict__ bandBase,
                                                 uint2* __restrict__ rec) {
    __shared__ unsigned h[NBAND];
    if (threadIdx.x < NBAND) h[threadIdx.x] = 0;
    __syncthreads();
    int i = blockIdx.x * 256 + threadIdx.x;
    if (i >= n) return;
    float2 p = x[i];
    int yi, xi; coord2idx(p.x, p.y, yi, xi);
    int b = yi / BROWS;
    unsigned r = atomicAdd(&h[b], 1u);
    unsigned dest = bandBase[b] + cnt[(size_t)b * nblkS + blockIdx.x] + r;
    rec[dest] = make_uint2((unsigned)i, ((unsigned)yi << 12) | (unsigned)xi);
}

// ---- Pass D: XCD-partitioned main compute over band-sorted records ----
__global__ __launch_bounds__(256) void main_k(
    const uint2* __restrict__ rec, const unsigned* __restrict__ bandBase,
    const float* __restrict__ g0, const float* __restrict__ g1,
    const float* __restrict__ g2, const float* __restrict__ g3,
    const float* __restrict__ g4, const float* __restrict__ g5,
    const float* __restrict__ g6, const float* __restrict__ g7,
    float* __restrict__ out)
{
#pragma clang fp contract(off)
    __shared__ float g6s[1653];
    __shared__ float g7s[435];
    for (int k = threadIdx.x; k < 1653; k += 256) g6s[k] = g6[k];
    for (int k = threadIdx.x; k < 435; k += 256) g7s[k] = g7[k];
    __syncthreads();

    // Blocks with blockIdx%8 == x land on XCD x (round-robin dispatch):
    // XCD x owns latitude bands 2x, 2x+1 -> per-XCD grid slice ~2.2MB, L2-fit.
    int xcd = blockIdx.x & 7;
    unsigned sper = gridDim.x >> 3;
    unsigned s0 = bandBase[2 * xcd], e0 = bandBase[2 * xcd + 1], e1 = bandBase[2 * xcd + 2];
    unsigned c0 = (e0 - s0 + 255u) >> 8, c1 = (e1 - e0 + 255u) >> 8;

    for (unsigned s = blockIdx.x >> 3; s < c0 + c1; s += sper) {
        unsigned gstart, gend;
        if (s < c0) { gstart = s0 + s * 256u; gend = e0; }
        else        { gstart = e0 + (s - c0) * 256u; gend = e1; }
        unsigned gi = gstart + threadIdx.x;
        if (gi >= gend) continue;

        uint2 rc = rec[gi];
        int yi = (int)(rc.y >> 12);
        int xi = (int)(rc.y & 4095u);

        float res[8];
        res[0] = g0[yi * LON_SHAPE + xi];   // level 0: blend collapses to v00

        constexpr int H[5] = {901, 451, 226, 113, 57};
        constexpr int W[5] = {1800, 900, 450, 225, 113};
        constexpr float SCY[5] = {
            (float)(901.0 / 1801.0), (float)(451.0 / 1801.0), (float)(226.0 / 1801.0),
            (float)(113.0 / 1801.0), (float)(57.0 / 1801.0)};
        constexpr float SCX[5] = {
            (float)(1800.0 / 3600.0), (float)(900.0 / 3600.0), (float)(450.0 / 3600.0),
            (float)(225.0 / 3600.0), (float)(113.0 / 3600.0)};
        const float* gg[5] = {g1, g2, g3, g4, g5};
        const float yif = (float)yi, xif = (float)xi;

        f32x2 pa[5], pb[5];
        float wyA[5], wxA[5];
        bool hiA[5];
#pragma unroll
        for (int i = 0; i < 5; ++i) {
            float sy = fmaxf((yif + 0.5f) * SCY[i] - 0.5f, 0.0f);
            float sx = fmaxf((xif + 0.5f) * SCX[i] - 0.5f, 0.0f);
            int y0 = (int)sy, x0 = (int)sx;
            wyA[i] = sy - (float)y0;
            wxA[i] = sx - (float)x0;
            int y1 = min(y0 + 1, H[i] - 1);
            int xb = min(x0, W[i] - 2);
            hiA[i] = x0 > xb;
            const float* __restrict__ g = gg[i];
            pa[i] = load_pair(g + y0 * W[i] + xb);
            pb[i] = load_pair(g + y1 * W[i] + xb);
        }
        {   // LDS levels 6..7 while global pairs are in flight
            constexpr int HL[2] = {29, 15};
            constexpr int WL[2] = {57, 29};
            constexpr float LSY[2] = {(float)(29.0 / 1801.0), (float)(15.0 / 1801.0)};
            constexpr float LSX[2] = {(float)(57.0 / 3600.0), (float)(29.0 / 3600.0)};
#pragma unroll
            for (int i = 0; i < 2; ++i) {
                const float* g = (i == 0) ? g6s : g7s;
                float sy = fmaxf((yif + 0.5f) * LSY[i] - 0.5f, 0.0f);
                float sx = fmaxf((xif + 0.5f) * LSX[i] - 0.5f, 0.0f);
                int y0 = (int)sy, x0 = (int)sx;
                float wy = sy - (float)y0, wx = sx - (float)x0;
                int y1 = min(y0 + 1, HL[i] - 1), x1 = min(x0 + 1, WL[i] - 1);
                float v00 = g[y0 * WL[i] + x0], v01 = g[y0 * WL[i] + x1];
                float v10 = g[y1 * WL[i] + x0], v11 = g[y1 * WL[i] + x1];
                float omwy = 1.0f - wy, omwx = 1.0f - wx;
                res[6 + i] = v00 * omwy * omwx + v01 * omwy * wx
                           + v10 * wy * omwx + v11 * wy * wx;
            }
        }
#pragma unroll
        for (int i = 0; i < 5; ++i) {
            float v00 = hiA[i] ? pa[i].y : pa[i].x;
            float v01 = pa[i].y;
            float v10 = hiA[i] ? pb[i].y : pb[i].x;
            float v11 = pb[i].y;
            float wy = wyA[i], wx = wxA[i];
            float omwy = 1.0f - wy, omwx = 1.0f - wx;
            res[1 + i] = v00 * omwy * omwx + v01 * omwy * wx
                       + v10 * wy * omwx + v11 * wy * wx;
        }

        // out[orig*8] is 32B-aligned -> exactly one write granule per point.
        float* op = out + (size_t)rc.x * 8;
        f32x4 lo = {res[0], res[1], res[2], res[3]};
        f32x4 hi = {res[4], res[5], res[6], res[7]};
        __builtin_nontemporal_store(lo, (f32x4*)op);
        __builtin_nontemporal_store(hi, (f32x4*)(op + 4));
    }
}

// ---- Fallback: round-7 direct kernel (145us, verified) ----
__global__ __launch_bounds__(256) void le_kernel(
    const float2* __restrict__ x,
    const float* __restrict__ g0, const float* __restrict__ g1,
    const float* __restrict__ g2, const float* __restrict__ g3,
    const float* __restrict__ g4, const float* __restrict__ g5,
    const float* __restrict__ g6, const float* __restrict__ g7,
    float* __restrict__ out, int n)
{
#pragma clang fp contract(off)
    __shared__ float g6s[1653];
    __shared__ float g7s[435];
    __shared__ f32x4 obuf[512];
    for (int k = threadIdx.x; k < 1653; k += 256) g6s[k] = g6[k];
    for (int k = threadIdx.x; k < 435; k += 256) g7s[k] = g7[k];
    __syncthreads();
    int idx = blockIdx.x * blockDim.x + threadIdx.x;
    int cidx = min(idx, n - 1);
    float2 p = x[cidx];
    int yi, xi; coord2idx(p.x, p.y, yi, xi);
    float res[8];
    res[0] = g0[yi * LON_SHAPE + xi];
    constexpr int H[8] = {1801, 901, 451, 226, 113, 57, 29, 15};
    constexpr int W[8] = {3600, 1800, 900, 450, 225, 113, 57, 29};
    const float yif = (float)yi, xif = (float)xi;
    auto bilin = [&](auto g, int Hi, int Wi, float sy_scale, float sx_scale) -> float {
#pragma clang fp contract(off)
        float sy = fmaxf((yif + 0.5f) * sy_scale - 0.5f, 0.0f);
        float sx = fmaxf((xif + 0.5f) * sx_scale - 0.5f, 0.0f);
        int y0 = (int)sy; int x0 = (int)sx;
        float wy = sy - (float)y0; float wx = sx - (float)x0;
        int y1 = min(y0 + 1, Hi - 1); int x1 = min(x0 + 1, Wi - 1);
        float v00 = g[y0 * Wi + x0]; float v01 = g[y0 * Wi + x1];
        float v10 = g[y1 * Wi + x0]; float v11 = g[y1 * Wi + x1];
        float omwy = 1.0f - wy, omwx = 1.0f - wx;
        return v00 * omwy * omwx + v01 * omwy * wx + v10 * wy * omwx + v11 * wy * wx;
    };
#define SC(i, dim, tot) ((float)((double)dim[i] / (double)tot))
    res[1] = bilin(g1, H[1], W[1], SC(1, H, LAT_SHAPE), SC(1, W, LON_SHAPE));
    res[2] = bilin(g2, H[2], W[2], SC(2, H, LAT_SHAPE), SC(2, W, LON_SHAPE));
    res[3] = bilin(g3, H[3], W[3], SC(3, H, LAT_SHAPE), SC(3, W, LON_SHAPE));
    res[4] = bilin(g4, H[4], W[4], SC(4, H, LAT_SHAPE), SC(4, W, LON_SHAPE));
    res[5] = bilin(g5, H[5], W[5], SC(5, H, LAT_SHAPE), SC(5, W, LON_SHAPE));
    res[6] = bilin((const float*)g6s, H[6], W[6], SC(6, H, LAT_SHAPE), SC(6, W, LON_SHAPE));
    res[7] = bilin((const float*)g7s, H[7], W[7], SC(7, H, LAT_SHAPE), SC(7, W, LON_SHAPE));
#undef SC
    f32x4 lo = {res[0], res[1], res[2], res[3]};
    f32x4 hi = {res[4], res[5], res[6], res[7]};
    obuf[2 * threadIdx.x] = lo;
    obuf[2 * threadIdx.x + 1] = hi;
    __syncthreads();
    const size_t total_f4 = (size_t)n * 2;
    const size_t base = (size_t)blockIdx.x * 512;
    f32x4* o4 = (f32x4*)out;
    int t = threadIdx.x;
    if (base + t < total_f4) __builtin_nontemporal_store(obuf[t], &o4[base + t]);
    if (base + 256 + t < total_f4) __builtin_nontemporal_store(obuf[256 + t], &o4[base + 256 + t]);
}

extern "C" void kernel_launch(void* const* d_in, const int* in_sizes, int n_in,
                              void* d_out, int out_size, void* d_ws, size_t ws_size,
                              hipStream_t stream) {
    const int GSZ[8] = {6483600, 1621800, 405900, 101700, 25425, 6441, 1653, 435};
    const float* xp = nullptr;
    const float* g[8] = {nullptr};
    int n = 0;
    for (int i = 0; i < n_in; ++i) {
        int s = in_sizes[i];
        if (s == 2 * NPTS) { xp = (const float*)d_in[i]; n = NPTS; continue; }
        for (int l = 0; l < 8; ++l)
            if (s == GSZ[l]) { g[l] = (const float*)d_in[i]; break; }
    }
    if (!xp) { xp = (const float*)d_in[0]; n = in_sizes[0] / 2; }
    for (int l = 0; l < 8; ++l)
        if (!g[l]) g[l] = (const float*)d_in[1 + l];

    const float2* x2 = (const float2*)xp;
    float* out = (float*)d_out;
    int nblkS = (n + 255) / 256;

    // ws layout: bandTotal[16] @0 | bandBase[17] @256B | cnt @4KB | rec
    size_t cntBytes = (size_t)NBAND * nblkS * 4;
    size_t recOff = (4096 + cntBytes + 255) & ~(size_t)255;
    size_t need = recOff + (size_t)n * 8;

    if (n > 0 && ws_size >= need) {
        unsigned* bandTotal = (unsigned*)d_ws;
        unsigned* bandBase = (unsigned*)((char*)d_ws + 256);
        unsigned* cnt = (unsigned*)((char*)d_ws + 4096);
        uint2* rec = (uint2*)((char*)d_ws + recOff);
        hist_k<<<nblkS, 256, 0, stream>>>(x2, n, nblkS, cnt);
        scanband_k<<<NBAND, 256, 0, stream>>>(cnt, nblkS, bandTotal);
        bandbase_k<<<1, 64, 0, stream>>>(bandTotal, bandBase);
        scatter_k<<<nblkS, 256, 0, stream>>>(x2, n, nblkS, cnt, bandBase, rec);
        main_k<<<8192, 256, 0, stream>>>(rec, bandBase, g[0], g[1], g[2], g[3],
                                         g[4], g[5], g[6], g[7], out);
    } else {
        le_kernel<<<nblkS, 256, 0, stream>>>(x2, g[0], g[1], g[2], g[3], g[4],
                                             g[5], g[6], g[7], out, n);
    }
}